// Round 3
// baseline (132.982 us; speedup 1.0000x reference)
//
#include <hip/hip_runtime.h>
#include <math.h>

// KnotNet: B=4096, L=256, S=4, H=64, NL=2.
// Insight: each braid step is a Givens rotation on rows p,p+1 of the state ->
// the whole per-layer scan is a single 4x4 matrix M (composition of Givens).
// Both layers share the gen sequence, so one pass composes M0 (theta[0]) and
// M1 (theta[1]) simultaneously. state' = LN(M1 @ LN(M0 @ state0)).

#define B_TOT 4096
#define LGEN  256

// ---------------- Kernel 1: compose Givens products + apply + LN ------------
// One wave (64 lanes) per batch. 4 waves per block -> 1024 blocks.
// Scan phase: lane (mat*4+col), mat in {0,1}, col in {0..3}, owns column `col`
// of matrix M_mat. Givens left-multiplication only mixes rows within a column,
// so the 256-step scan needs NO cross-lane traffic. gen is wave-uniform ->
// uniform branches (no divergence).
__global__ __launch_bounds__(256) void knot_state_kernel(
    const int*   __restrict__ braids,     // [B,256]
    const float* __restrict__ init_state, // [4,64]
    const float* __restrict__ thetas,     // [2,3]
    const float* __restrict__ lnw,        // [2,64]
    const float* __restrict__ lnb,        // [2,64]
    float*       __restrict__ flat_out)   // [B,256] ws
{
    __shared__ int4 sgen[4][64];
    const int lane = threadIdx.x & 63;
    const int wv   = threadIdx.x >> 6;
    const int b    = (blockIdx.x << 2) + wv;

    // stage this wave's braid row into LDS (1KB/wave)
    sgen[wv][lane] = reinterpret_cast<const int4*>(braids)[b * 64 + lane];

    const int mat = (lane >> 2) & 1;   // lanes 0-3: M0 cols, 4-7: M1 cols (rest redundant)
    const int col = lane & 3;
    const float cp0 = cosf(thetas[mat * 3 + 0]), sp0 = sinf(thetas[mat * 3 + 0]);
    const float cp1 = cosf(thetas[mat * 3 + 1]), sp1 = sinf(thetas[mat * 3 + 1]);
    const float cp2 = cosf(thetas[mat * 3 + 2]), sp2 = sinf(thetas[mat * 3 + 2]);

    // column `col` of M (identity init)
    float m0 = (col == 0) ? 1.f : 0.f;
    float m1 = (col == 1) ? 1.f : 0.f;
    float m2 = (col == 2) ? 1.f : 0.f;
    float m3 = (col == 3) ? 1.f : 0.f;

    __syncthreads();

    #pragma unroll 1
    for (int t4 = 0; t4 < 64; ++t4) {
        const int4 gq = sgen[wv][t4];   // broadcast read (same addr, all lanes)
        #pragma unroll
        for (int j = 0; j < 4; ++j) {
            const int g = (j == 0) ? gq.x : (j == 1) ? gq.y : (j == 2) ? gq.z : gq.w;
            if (g != 0) {                          // wave-uniform
                const float sgn = (g > 0) ? 1.f : -1.f;
                const int   p   = ((g > 0) ? g : -g) - 1;   // 0..2, uniform
                if (p == 0) {
                    const float c = cp0, s = sp0 * sgn;
                    const float u = m0, v = m1;
                    m0 = fmaf(u, c, -v * s);
                    m1 = fmaf(u, s,  v * c);
                } else if (p == 1) {
                    const float c = cp1, s = sp1 * sgn;
                    const float u = m1, v = m2;
                    m1 = fmaf(u, c, -v * s);
                    m2 = fmaf(u, s,  v * c);
                } else {
                    const float c = cp2, s = sp2 * sgn;
                    const float u = m2, v = m3;
                    m2 = fmaf(u, c, -v * s);
                    m3 = fmaf(u, s,  v * c);
                }
            }
        }
    }

    // broadcast both 4x4 matrices to all lanes (lane k holds col k of M0, 4+k col k of M1)
    float M0[4][4], M1[4][4];
    #pragma unroll
    for (int k = 0; k < 4; ++k) {
        M0[0][k] = __shfl(m0, k);     M1[0][k] = __shfl(m0, 4 + k);
        M0[1][k] = __shfl(m1, k);     M1[1][k] = __shfl(m1, 4 + k);
        M0[2][k] = __shfl(m2, k);     M1[2][k] = __shfl(m2, 4 + k);
        M0[3][k] = __shfl(m3, k);     M1[3][k] = __shfl(m3, 4 + k);
    }

    // lane = hidden index; each lane holds column `lane` of the 4x64 state
    float st0[4];
    #pragma unroll
    for (int i = 0; i < 4; ++i) st0[i] = init_state[i * 64 + lane];

    const float lw0 = lnw[lane],      lb0 = lnb[lane];
    const float lw1 = lnw[64 + lane], lb1 = lnb[64 + lane];

    // layer 0: rotate + LN
    float x[4];
    #pragma unroll
    for (int i = 0; i < 4; ++i)
        x[i] = fmaf(M0[i][0], st0[0], fmaf(M0[i][1], st0[1],
                 fmaf(M0[i][2], st0[2], M0[i][3] * st0[3])));

    #pragma unroll
    for (int i = 0; i < 4; ++i) {
        float s1 = x[i], s2 = x[i] * x[i];
        #pragma unroll
        for (int off = 32; off > 0; off >>= 1) {
            s1 += __shfl_xor(s1, off);
            s2 += __shfl_xor(s2, off);
        }
        const float mu  = s1 * 0.015625f;                 // /64
        const float var = fmaf(s2, 0.015625f, -mu * mu);
        const float inv = rsqrtf(var + 1e-5f);
        x[i] = fmaf((x[i] - mu) * inv, lw0, lb0);
    }

    // layer 1: rotate + LN
    float y[4];
    #pragma unroll
    for (int i = 0; i < 4; ++i)
        y[i] = fmaf(M1[i][0], x[0], fmaf(M1[i][1], x[1],
                 fmaf(M1[i][2], x[2], M1[i][3] * x[3])));

    #pragma unroll
    for (int i = 0; i < 4; ++i) {
        float s1 = y[i], s2 = y[i] * y[i];
        #pragma unroll
        for (int off = 32; off > 0; off >>= 1) {
            s1 += __shfl_xor(s1, off);
            s2 += __shfl_xor(s2, off);
        }
        const float mu  = s1 * 0.015625f;
        const float var = fmaf(s2, 0.015625f, -mu * mu);
        const float inv = rsqrtf(var + 1e-5f);
        y[i] = fmaf((y[i] - mu) * inv, lw1, lb1);
    }

    // write flat state [b][s*64+h]
    #pragma unroll
    for (int i = 0; i < 4; ++i)
        flat_out[b * 256 + i * 64 + lane] = y[i];
}

// ---------------- Kernel 2: MLP 256->128(relu)->64(relu)->2 -----------------
// 256 blocks x 16 batches. flat tile staged in LDS; all LDS reads in the GEMM
// loops are wave-uniform addresses (free broadcast).
__device__ __forceinline__ float dot4(float4 a, float4 b, float acc) {
    acc = fmaf(a.x, b.x, acc);
    acc = fmaf(a.y, b.y, acc);
    acc = fmaf(a.z, b.z, acc);
    acc = fmaf(a.w, b.w, acc);
    return acc;
}

__global__ __launch_bounds__(256) void knot_mlp_kernel(
    const float* __restrict__ flat,  // [B,256] ws
    const float* __restrict__ w1,    // [128,256]
    const float* __restrict__ b1,    // [128]
    const float* __restrict__ w2,    // [64,128]
    const float* __restrict__ b2,    // [64]
    const float* __restrict__ w3,    // [2,64]
    const float* __restrict__ b3,    // [2]
    float*       __restrict__ out)   // [2*B] : [sigmoid(l0) ; l1]
{
    __shared__ float fl[16][256];    // 16KB
    __shared__ float h1s[16][128];   // 8KB
    __shared__ float h2s[16][65];    // padded: phase-3 reads stride 64 would bank-conflict

    const int tid   = threadIdx.x;
    const int bbase = blockIdx.x * 16;

    // stage 16 batches of flat (coalesced float4)
    {
        const float4* src = reinterpret_cast<const float4*>(flat + (size_t)bbase * 256);
        float4* dst = reinterpret_cast<float4*>(&fl[0][0]);
        #pragma unroll
        for (int r = 0; r < 4; ++r)
            dst[r * 256 + tid] = src[r * 256 + tid];
    }
    __syncthreads();

    // ---- h1 = relu(W1 @ flat + b1): thread -> outputs {o, o+64}, 4 batches
    {
        const int o = tid & 63;
        const int q = tid >> 6;          // 0..3 -> batches q*4 .. q*4+3
        float acc0[4] = {0.f, 0.f, 0.f, 0.f};
        float acc1[4] = {0.f, 0.f, 0.f, 0.f};
        const float* w1r0 = w1 + (size_t)o * 256;
        const float* w1r1 = w1 + (size_t)(o + 64) * 256;
        for (int k = 0; k < 256; k += 4) {
            const float4 wa = *reinterpret_cast<const float4*>(w1r0 + k);
            const float4 wb = *reinterpret_cast<const float4*>(w1r1 + k);
            #pragma unroll
            for (int bb = 0; bb < 4; ++bb) {
                const float4 f = *reinterpret_cast<const float4*>(&fl[q * 4 + bb][k]);
                acc0[bb] = dot4(wa, f, acc0[bb]);
                acc1[bb] = dot4(wb, f, acc1[bb]);
            }
        }
        const float bo0 = b1[o], bo1 = b1[o + 64];
        #pragma unroll
        for (int bb = 0; bb < 4; ++bb) {
            h1s[q * 4 + bb][o]      = fmaxf(acc0[bb] + bo0, 0.f);
            h1s[q * 4 + bb][o + 64] = fmaxf(acc1[bb] + bo1, 0.f);
        }
    }
    __syncthreads();

    // ---- h2 = relu(W2 @ h1 + b2): thread -> output o2, 4 batches
    {
        const int o = tid & 63;
        const int q = tid >> 6;
        float acc[4] = {0.f, 0.f, 0.f, 0.f};
        const float* w2r = w2 + (size_t)o * 128;
        for (int k = 0; k < 128; k += 4) {
            const float4 wv = *reinterpret_cast<const float4*>(w2r + k);
            #pragma unroll
            for (int bb = 0; bb < 4; ++bb) {
                const float4 f = *reinterpret_cast<const float4*>(&h1s[q * 4 + bb][k]);
                acc[bb] = dot4(wv, f, acc[bb]);
            }
        }
        const float bo = b2[o];
        #pragma unroll
        for (int bb = 0; bb < 4; ++bb)
            h2s[q * 4 + bb][o] = fmaxf(acc[bb] + bo, 0.f);
    }
    __syncthreads();

    // ---- out = W3 @ h2 + b3; out0 -> sigmoid, out1 raw
    if (tid < 32) {
        const int bb = tid >> 1;
        const int j  = tid & 1;
        const float* w3r = w3 + j * 64;
        float acc = b3[j];
        for (int k = 0; k < 64; ++k)
            acc = fmaf(w3r[k], h2s[bb][k], acc);
        const int bg = bbase + bb;
        if (j == 0) out[bg]         = 1.f / (1.f + expf(-acc));
        else        out[B_TOT + bg] = acc;
    }
}

extern "C" void kernel_launch(void* const* d_in, const int* in_sizes, int n_in,
                              void* d_out, int out_size, void* d_ws, size_t ws_size,
                              hipStream_t stream) {
    const int*   braids     = (const int*)  d_in[0];
    const float* init_state = (const float*)d_in[1];
    const float* thetas     = (const float*)d_in[2];
    const float* lnw        = (const float*)d_in[3];
    const float* lnb        = (const float*)d_in[4];
    const float* w1         = (const float*)d_in[5];
    const float* b1         = (const float*)d_in[6];
    const float* w2         = (const float*)d_in[7];
    const float* b2         = (const float*)d_in[8];
    const float* w3         = (const float*)d_in[9];
    const float* b3         = (const float*)d_in[10];
    float* out = (float*)d_out;
    float* ws_flat = (float*)d_ws;   // needs B*256*4 = 4MB

    knot_state_kernel<<<B_TOT / 4, 256, 0, stream>>>(
        braids, init_state, thetas, lnw, lnb, ws_flat);
    knot_mlp_kernel<<<B_TOT / 16, 256, 0, stream>>>(
        ws_flat, w1, b1, w2, b2, w3, b3, out);
}

// Round 11
// 109.943 us; speedup vs baseline: 1.2095x; 1.2095x over previous
//
#include <hip/hip_runtime.h>
#include <math.h>

// KnotNet: B=4096, L=256, S=4, H=64, NL=2.
// Braid scan = product of Givens rotations -> compose per-batch 4x4 matrices.
// Round-3 data: wave-per-batch branchy scan = 42.5us, ~100 cyc/step, 62/64
// lanes redundant. This round: per-LANE-batch branchless scan, chunked
// (associative) composition for parallelism:
//   K1: 256 blocks (64 batch-groups x 4 chunk-groups), 4 waves x 16 steps/lane,
//       in-block combine -> 4x4 partial per (batch, cg, layer) in ws.
//   K2: wave-per-batch: chain 4 partials, apply state, 2x LayerNorm -> flat.
//   K3: MLP 256->128->64->2 (unchanged from round 0, which passed).

#define B_TOT 4096
#define LGEN  256

// =========================== K1: branchless scan ===========================
// blockIdx = bg*4 + cg. Wave wv covers steps [cg*64 + wv*16, +16) for the 64
// batches bg*64..bg*64+63 (lane = batch). All lanes run identical code; the
// generator only selects (c,s) coefficients via cndmask -> zero divergence.
__global__ __launch_bounds__(256) void knot_scan_kernel(
    const int*   __restrict__ braids,   // [B,256]
    const float* __restrict__ thetas,   // [2,3]
    float*       __restrict__ qpart)    // [cg][layer][4096][16] floats (2MB)
{
    const int tid  = threadIdx.x;
    const int lane = tid & 63;
    const int wv   = tid >> 6;
    const int bg   = blockIdx.x >> 2;
    const int cg   = blockIdx.x & 3;
    const int b    = bg * 64 + lane;
    const int s0   = cg * 64 + wv * 16;

    // 16 gens for this (batch, sub-chunk): 4x int4, lane-strided (1KB apart).
    const int4* gp = reinterpret_cast<const int4*>(braids + b * 256 + s0);
    const int4 ga = gp[0], gb = gp[1], gc = gp[2], gd = gp[3];
    int gg[16];
    gg[0]=ga.x; gg[1]=ga.y; gg[2]=ga.z; gg[3]=ga.w;
    gg[4]=gb.x; gg[5]=gb.y; gg[6]=gb.z; gg[7]=gb.w;
    gg[8]=gc.x; gg[9]=gc.y; gg[10]=gc.z; gg[11]=gc.w;
    gg[12]=gd.x; gg[13]=gd.y; gg[14]=gd.z; gg[15]=gd.w;

    // trig coefficients (redundant per thread; ~150 instr once)
    float ct[2][3], st[2][3];
    #pragma unroll
    for (int L = 0; L < 2; ++L)
        #pragma unroll
        for (int k = 0; k < 3; ++k) {
            const float th = thetas[L * 3 + k];
            ct[L][k] = cosf(th);
            st[L][k] = sinf(th);
        }

    // two 4x4 matrices (layer 0/1), identity init. All indices compile-time.
    float m[2][4][4];
    #pragma unroll
    for (int L = 0; L < 2; ++L)
        #pragma unroll
        for (int r = 0; r < 4; ++r)
            #pragma unroll
            for (int c = 0; c < 4; ++c)
                m[L][r][c] = (r == c) ? 1.f : 0.f;

    // 16 branchless steps. Step = three fixed-position rotations R0,R1,R2 of
    // which at most one is non-identity (c=1,s=0 otherwise -> exact identity).
    #pragma unroll
    for (int i = 0; i < 16; ++i) {
        const int  g  = gg[i];
        const int  a  = (g < 0) ? -g : g;
        const bool ng = (g < 0);
        const bool e1 = (a == 1), e2 = (a == 2), e3 = (a == 3);
        #pragma unroll
        for (int L = 0; L < 2; ++L) {
            #pragma unroll
            for (int k = 0; k < 3; ++k) {
                const bool hit = (k == 0) ? e1 : (k == 1) ? e2 : e3;
                const float c = hit ? ct[L][k] : 1.0f;
                float s = hit ? st[L][k] : 0.0f;
                s = ng ? -s : s;
                #pragma unroll
                for (int col = 0; col < 4; ++col) {
                    const float u = m[L][k][col], v = m[L][k + 1][col];
                    m[L][k][col]     = fmaf(u, c, -(v * s));   // u*c - v*s
                    m[L][k + 1][col] = fmaf(v, c, u * s);      // u*s + v*c
                }
            }
        }
    }

    // in-block combine: P_block = P_w3 @ P_w2 @ P_w1 @ P_w0 per batch.
    // LDS [layer][wave][val][lane]: stride-1 across lanes -> conflict-free.
    __shared__ float lp[2][4][16][64];   // 32KB
    #pragma unroll
    for (int L = 0; L < 2; ++L)
        #pragma unroll
        for (int v = 0; v < 16; ++v)
            lp[L][wv][v][lane] = m[L][v >> 2][v & 3];
    __syncthreads();

    if (wv == 0) {
        #pragma unroll
        for (int L = 0; L < 2; ++L) {
            float M[4][4];
            #pragma unroll
            for (int r = 0; r < 4; ++r)
                #pragma unroll
                for (int c = 0; c < 4; ++c)
                    M[r][c] = m[L][r][c];          // wave0 = earliest chunk
            #pragma unroll
            for (int w2 = 1; w2 < 4; ++w2) {       // later chunks multiply left
                float P[4][4];
                #pragma unroll
                for (int r = 0; r < 4; ++r)
                    #pragma unroll
                    for (int c = 0; c < 4; ++c)
                        P[r][c] = lp[L][w2][r * 4 + c][lane];
                float N[4][4];
                #pragma unroll
                for (int r = 0; r < 4; ++r)
                    #pragma unroll
                    for (int c = 0; c < 4; ++c)
                        N[r][c] = fmaf(P[r][0], M[0][c], fmaf(P[r][1], M[1][c],
                                  fmaf(P[r][2], M[2][c], P[r][3] * M[3][c])));
                #pragma unroll
                for (int r = 0; r < 4; ++r)
                    #pragma unroll
                    for (int c = 0; c < 4; ++c)
                        M[r][c] = N[r][c];
            }
            float4* dst = reinterpret_cast<float4*>(
                qpart + ((size_t)(cg * 2 + L) * 4096 + b) * 16);
            #pragma unroll
            for (int r = 0; r < 4; ++r)
                dst[r] = make_float4(M[r][0], M[r][1], M[r][2], M[r][3]);
        }
    }
}

// ================== K2: combine partials + apply + LayerNorm ================
// Wave per batch (lane = hidden dim). Chain the 4 chunk-partials per layer
// (broadcast float4 loads, redundant 384 FMA per lane), then rotate + LN x2.
__global__ __launch_bounds__(256) void knot_apply_kernel(
    const float* __restrict__ qpart,      // [cg][layer][4096][16]
    const float* __restrict__ init_state, // [4,64]
    const float* __restrict__ lnw,        // [2,64]
    const float* __restrict__ lnb,        // [2,64]
    float*       __restrict__ flat_out)   // [B,256]
{
    const int lane = threadIdx.x & 63;
    const int wv   = threadIdx.x >> 6;
    const int b    = blockIdx.x * 4 + wv;

    float MM[2][4][4];
    #pragma unroll
    for (int L = 0; L < 2; ++L) {
        const float4* q0 = reinterpret_cast<const float4*>(
            qpart + ((size_t)(0 * 2 + L) * 4096 + b) * 16);
        #pragma unroll
        for (int r = 0; r < 4; ++r) {
            const float4 t = q0[r];
            MM[L][r][0] = t.x; MM[L][r][1] = t.y; MM[L][r][2] = t.z; MM[L][r][3] = t.w;
        }
        #pragma unroll
        for (int c = 1; c < 4; ++c) {
            const float4* qc = reinterpret_cast<const float4*>(
                qpart + ((size_t)(c * 2 + L) * 4096 + b) * 16);
            float P[4][4];
            #pragma unroll
            for (int r = 0; r < 4; ++r) {
                const float4 t = qc[r];
                P[r][0] = t.x; P[r][1] = t.y; P[r][2] = t.z; P[r][3] = t.w;
            }
            float N[4][4];
            #pragma unroll
            for (int r = 0; r < 4; ++r)
                #pragma unroll
                for (int cc = 0; cc < 4; ++cc)
                    N[r][cc] = fmaf(P[r][0], MM[L][0][cc], fmaf(P[r][1], MM[L][1][cc],
                               fmaf(P[r][2], MM[L][2][cc], P[r][3] * MM[L][3][cc])));
            #pragma unroll
            for (int r = 0; r < 4; ++r)
                #pragma unroll
                for (int cc = 0; cc < 4; ++cc)
                    MM[L][r][cc] = N[r][cc];
        }
    }

    float st0[4];
    #pragma unroll
    for (int i = 0; i < 4; ++i) st0[i] = init_state[i * 64 + lane];
    const float lw0 = lnw[lane],      lb0 = lnb[lane];
    const float lw1 = lnw[64 + lane], lb1 = lnb[64 + lane];

    float x[4];
    #pragma unroll
    for (int i = 0; i < 4; ++i)
        x[i] = fmaf(MM[0][i][0], st0[0], fmaf(MM[0][i][1], st0[1],
               fmaf(MM[0][i][2], st0[2], MM[0][i][3] * st0[3])));
    #pragma unroll
    for (int i = 0; i < 4; ++i) {
        float s1 = x[i], s2 = x[i] * x[i];
        #pragma unroll
        for (int off = 32; off > 0; off >>= 1) {
            s1 += __shfl_xor(s1, off);
            s2 += __shfl_xor(s2, off);
        }
        const float mu  = s1 * 0.015625f;
        const float var = fmaf(s2, 0.015625f, -mu * mu);
        const float inv = rsqrtf(var + 1e-5f);
        x[i] = fmaf((x[i] - mu) * inv, lw0, lb0);
    }

    float y[4];
    #pragma unroll
    for (int i = 0; i < 4; ++i)
        y[i] = fmaf(MM[1][i][0], x[0], fmaf(MM[1][i][1], x[1],
               fmaf(MM[1][i][2], x[2], MM[1][i][3] * x[3])));
    #pragma unroll
    for (int i = 0; i < 4; ++i) {
        float s1 = y[i], s2 = y[i] * y[i];
        #pragma unroll
        for (int off = 32; off > 0; off >>= 1) {
            s1 += __shfl_xor(s1, off);
            s2 += __shfl_xor(s2, off);
        }
        const float mu  = s1 * 0.015625f;
        const float var = fmaf(s2, 0.015625f, -mu * mu);
        const float inv = rsqrtf(var + 1e-5f);
        y[i] = fmaf((y[i] - mu) * inv, lw1, lb1);
    }

    #pragma unroll
    for (int i = 0; i < 4; ++i)
        flat_out[b * 256 + i * 64 + lane] = y[i];
}

// ============== Fallback (round-0 monolithic scan, proven correct) ==========
__global__ __launch_bounds__(256) void knot_state_kernel(
    const int*   __restrict__ braids,
    const float* __restrict__ init_state,
    const float* __restrict__ thetas,
    const float* __restrict__ lnw,
    const float* __restrict__ lnb,
    float*       __restrict__ flat_out)
{
    __shared__ int4 sgen[4][64];
    const int lane = threadIdx.x & 63;
    const int wv   = threadIdx.x >> 6;
    const int b    = (blockIdx.x << 2) + wv;
    sgen[wv][lane] = reinterpret_cast<const int4*>(braids)[b * 64 + lane];
    const int mat = (lane >> 2) & 1;
    const int col = lane & 3;
    const float cp0 = cosf(thetas[mat * 3 + 0]), sp0 = sinf(thetas[mat * 3 + 0]);
    const float cp1 = cosf(thetas[mat * 3 + 1]), sp1 = sinf(thetas[mat * 3 + 1]);
    const float cp2 = cosf(thetas[mat * 3 + 2]), sp2 = sinf(thetas[mat * 3 + 2]);
    float m0 = (col == 0) ? 1.f : 0.f;
    float m1 = (col == 1) ? 1.f : 0.f;
    float m2 = (col == 2) ? 1.f : 0.f;
    float m3 = (col == 3) ? 1.f : 0.f;
    __syncthreads();
    #pragma unroll 1
    for (int t4 = 0; t4 < 64; ++t4) {
        const int4 gq = sgen[wv][t4];
        #pragma unroll
        for (int j = 0; j < 4; ++j) {
            const int g = (j == 0) ? gq.x : (j == 1) ? gq.y : (j == 2) ? gq.z : gq.w;
            if (g != 0) {
                const float sgn = (g > 0) ? 1.f : -1.f;
                const int   p   = ((g > 0) ? g : -g) - 1;
                if (p == 0) {
                    const float c = cp0, s = sp0 * sgn;
                    const float u = m0, v = m1;
                    m0 = fmaf(u, c, -v * s); m1 = fmaf(u, s, v * c);
                } else if (p == 1) {
                    const float c = cp1, s = sp1 * sgn;
                    const float u = m1, v = m2;
                    m1 = fmaf(u, c, -v * s); m2 = fmaf(u, s, v * c);
                } else {
                    const float c = cp2, s = sp2 * sgn;
                    const float u = m2, v = m3;
                    m2 = fmaf(u, c, -v * s); m3 = fmaf(u, s, v * c);
                }
            }
        }
    }
    float M0[4][4], M1[4][4];
    #pragma unroll
    for (int k = 0; k < 4; ++k) {
        M0[0][k] = __shfl(m0, k);     M1[0][k] = __shfl(m0, 4 + k);
        M0[1][k] = __shfl(m1, k);     M1[1][k] = __shfl(m1, 4 + k);
        M0[2][k] = __shfl(m2, k);     M1[2][k] = __shfl(m2, 4 + k);
        M0[3][k] = __shfl(m3, k);     M1[3][k] = __shfl(m3, 4 + k);
    }
    float st0[4];
    #pragma unroll
    for (int i = 0; i < 4; ++i) st0[i] = init_state[i * 64 + lane];
    const float lw0 = lnw[lane],      lb0 = lnb[lane];
    const float lw1 = lnw[64 + lane], lb1 = lnb[64 + lane];
    float x[4];
    #pragma unroll
    for (int i = 0; i < 4; ++i)
        x[i] = fmaf(M0[i][0], st0[0], fmaf(M0[i][1], st0[1],
               fmaf(M0[i][2], st0[2], M0[i][3] * st0[3])));
    #pragma unroll
    for (int i = 0; i < 4; ++i) {
        float s1 = x[i], s2 = x[i] * x[i];
        #pragma unroll
        for (int off = 32; off > 0; off >>= 1) { s1 += __shfl_xor(s1, off); s2 += __shfl_xor(s2, off); }
        const float mu = s1 * 0.015625f;
        const float var = fmaf(s2, 0.015625f, -mu * mu);
        const float inv = rsqrtf(var + 1e-5f);
        x[i] = fmaf((x[i] - mu) * inv, lw0, lb0);
    }
    float y[4];
    #pragma unroll
    for (int i = 0; i < 4; ++i)
        y[i] = fmaf(M1[i][0], x[0], fmaf(M1[i][1], x[1],
               fmaf(M1[i][2], x[2], M1[i][3] * x[3])));
    #pragma unroll
    for (int i = 0; i < 4; ++i) {
        float s1 = y[i], s2 = y[i] * y[i];
        #pragma unroll
        for (int off = 32; off > 0; off >>= 1) { s1 += __shfl_xor(s1, off); s2 += __shfl_xor(s2, off); }
        const float mu = s1 * 0.015625f;
        const float var = fmaf(s2, 0.015625f, -mu * mu);
        const float inv = rsqrtf(var + 1e-5f);
        y[i] = fmaf((y[i] - mu) * inv, lw1, lb1);
    }
    #pragma unroll
    for (int i = 0; i < 4; ++i)
        flat_out[b * 256 + i * 64 + lane] = y[i];
}

// ======================= K3: MLP (unchanged, passed) ========================
__device__ __forceinline__ float dot4(float4 a, float4 b, float acc) {
    acc = fmaf(a.x, b.x, acc);
    acc = fmaf(a.y, b.y, acc);
    acc = fmaf(a.z, b.z, acc);
    acc = fmaf(a.w, b.w, acc);
    return acc;
}

__global__ __launch_bounds__(256) void knot_mlp_kernel(
    const float* __restrict__ flat,
    const float* __restrict__ w1, const float* __restrict__ b1,
    const float* __restrict__ w2, const float* __restrict__ b2,
    const float* __restrict__ w3, const float* __restrict__ b3,
    float*       __restrict__ out)
{
    __shared__ float fl[16][256];
    __shared__ float h1s[16][128];
    __shared__ float h2s[16][65];

    const int tid   = threadIdx.x;
    const int bbase = blockIdx.x * 16;

    {
        const float4* src = reinterpret_cast<const float4*>(flat + (size_t)bbase * 256);
        float4* dst = reinterpret_cast<float4*>(&fl[0][0]);
        #pragma unroll
        for (int r = 0; r < 4; ++r)
            dst[r * 256 + tid] = src[r * 256 + tid];
    }
    __syncthreads();

    {
        const int o = tid & 63;
        const int q = tid >> 6;
        float acc0[4] = {0.f, 0.f, 0.f, 0.f};
        float acc1[4] = {0.f, 0.f, 0.f, 0.f};
        const float* w1r0 = w1 + (size_t)o * 256;
        const float* w1r1 = w1 + (size_t)(o + 64) * 256;
        for (int k = 0; k < 256; k += 4) {
            const float4 wa = *reinterpret_cast<const float4*>(w1r0 + k);
            const float4 wb = *reinterpret_cast<const float4*>(w1r1 + k);
            #pragma unroll
            for (int bb = 0; bb < 4; ++bb) {
                const float4 f = *reinterpret_cast<const float4*>(&fl[q * 4 + bb][k]);
                acc0[bb] = dot4(wa, f, acc0[bb]);
                acc1[bb] = dot4(wb, f, acc1[bb]);
            }
        }
        const float bo0 = b1[o], bo1 = b1[o + 64];
        #pragma unroll
        for (int bb = 0; bb < 4; ++bb) {
            h1s[q * 4 + bb][o]      = fmaxf(acc0[bb] + bo0, 0.f);
            h1s[q * 4 + bb][o + 64] = fmaxf(acc1[bb] + bo1, 0.f);
        }
    }
    __syncthreads();

    {
        const int o = tid & 63;
        const int q = tid >> 6;
        float acc[4] = {0.f, 0.f, 0.f, 0.f};
        const float* w2r = w2 + (size_t)o * 128;
        for (int k = 0; k < 128; k += 4) {
            const float4 wv = *reinterpret_cast<const float4*>(w2r + k);
            #pragma unroll
            for (int bb = 0; bb < 4; ++bb) {
                const float4 f = *reinterpret_cast<const float4*>(&h1s[q * 4 + bb][k]);
                acc[bb] = dot4(wv, f, acc[bb]);
            }
        }
        const float bo = b2[o];
        #pragma unroll
        for (int bb = 0; bb < 4; ++bb)
            h2s[q * 4 + bb][o] = fmaxf(acc[bb] + bo, 0.f);
    }
    __syncthreads();

    if (tid < 32) {
        const int bb = tid >> 1;
        const int j  = tid & 1;
        const float* w3r = w3 + j * 64;
        float acc = b3[j];
        for (int k = 0; k < 64; ++k)
            acc = fmaf(w3r[k], h2s[bb][k], acc);
        const int bg = bbase + bb;
        if (j == 0) out[bg]         = 1.f / (1.f + expf(-acc));
        else        out[B_TOT + bg] = acc;
    }
}

extern "C" void kernel_launch(void* const* d_in, const int* in_sizes, int n_in,
                              void* d_out, int out_size, void* d_ws, size_t ws_size,
                              hipStream_t stream) {
    const int*   braids     = (const int*)  d_in[0];
    const float* init_state = (const float*)d_in[1];
    const float* thetas     = (const float*)d_in[2];
    const float* lnw        = (const float*)d_in[3];
    const float* lnb        = (const float*)d_in[4];
    const float* w1         = (const float*)d_in[5];
    const float* b1         = (const float*)d_in[6];
    const float* w2         = (const float*)d_in[7];
    const float* b2         = (const float*)d_in[8];
    const float* w3         = (const float*)d_in[9];
    const float* b3         = (const float*)d_in[10];
    float* out = (float*)d_out;

    if (ws_size >= (size_t)(6u << 20)) {
        float* qpart = (float*)d_ws;                              // 2MB
        float* flat  = (float*)((char*)d_ws + (2u << 20));        // 4MB
        knot_scan_kernel<<<256, 256, 0, stream>>>(braids, thetas, qpart);
        knot_apply_kernel<<<B_TOT / 4, 256, 0, stream>>>(
            qpart, init_state, lnw, lnb, flat);
        knot_mlp_kernel<<<B_TOT / 16, 256, 0, stream>>>(
            flat, w1, b1, w2, b2, w3, b3, out);
    } else {
        float* flat = (float*)d_ws;                               // 4MB
        knot_state_kernel<<<B_TOT / 4, 256, 0, stream>>>(
            braids, init_state, thetas, lnw, lnb, flat);
        knot_mlp_kernel<<<B_TOT / 16, 256, 0, stream>>>(
            flat, w1, b1, w2, b2, w3, b3, out);
    }
}